// Round 1
// 918.218 us; speedup vs baseline: 1.0163x; 1.0163x over previous
//
#include <hip/hip_runtime.h>

#define HIDDEN 2048
#define QUANT  16
#define BATCH  8192
#define HALFD  1024

// GEMM geometry: 256x256 tile, ring-4 of BK=32 K-tiles, 8 waves (2m x 4n)
#define BM 256
#define BN 256
#define BKT 32
#define NT (HIDDEN / BKT)            // 64 K-tiles
#define A_HALFS (BM * BKT)           // 8192 halfs = 16 KB per A slot
#define SLOT_HALFS (2 * A_HALFS)     // A+B per slot = 32 KB; x4 slots = 128 KB

typedef _Float16 half8  __attribute__((ext_vector_type(8)));
typedef float    floatx16 __attribute__((ext_vector_type(16)));

__device__ __forceinline__ void load_lds16(const void* gptr, void* lptr) {
  __builtin_amdgcn_global_load_lds(
      (const __attribute__((address_space(1))) void*)gptr,
      (__attribute__((address_space(3))) void*)lptr, 16, 0, 0);
}

// exact-GELU via Abramowitz-Stegun 7.1.26 erf (|eps_erf| <= 1.5e-7)
__device__ __forceinline__ float gelu_exact(float v) {
  const float z  = 0.7071067811865476f * v;
  const float az = fabsf(z);
  const float t  = __builtin_amdgcn_rcpf(1.0f + 0.3275911f * az);
  const float p  = t * (0.254829592f +
                   t * (-0.284496736f +
                   t * (1.421413741f +
                   t * (-1.453152027f +
                   t * 1.061405429f))));
  float er = 1.0f - p * __expf(-az * az);
  er = copysignf(er, z);
  return 0.5f * v * (1.0f + er);
}

// ---- x fp32 -> fp16 ----
__global__ __launch_bounds__(256) void convert_x_kernel(const float* __restrict__ x,
                                                        _Float16* __restrict__ xh) {
  const int i = (blockIdx.x * 256 + threadIdx.x) * 8;
  const float4 a = *(const float4*)(x + i);
  const float4 b = *(const float4*)(x + i + 4);
  half8 h;
  h[0] = (_Float16)a.x; h[1] = (_Float16)a.y; h[2] = (_Float16)a.z; h[3] = (_Float16)a.w;
  h[4] = (_Float16)b.x; h[5] = (_Float16)b.y; h[6] = (_Float16)b.z; h[7] = (_Float16)b.w;
  *(half8*)(xh + i) = h;
}

// ---- W1 [Q][H][N] fp32 -> W1T [Q][N][H] fp16 ----
__global__ __launch_bounds__(256) void transpose_w1_kernel(const float* __restrict__ W1,
                                                           _Float16* __restrict__ W1T) {
  __shared__ float tile[64][33];
  const int q  = blockIdx.z;
  const int h0 = blockIdx.y * 64;
  const int n0 = blockIdx.x * 32;
  const float* src = W1 + (size_t)q * HIDDEN * HALFD;
  _Float16*    dst = W1T + (size_t)q * HALFD * HIDDEN;
  const int t  = threadIdx.x;
  const int lr = t >> 3;
  const int lc = (t & 7) * 4;
  #pragma unroll
  for (int j = 0; j < 2; ++j) {
    const float4 v = *(const float4*)(src + (size_t)(h0 + lr + 32 * j) * HALFD + n0 + lc);
    tile[lr + 32 * j][lc + 0] = v.x;
    tile[lr + 32 * j][lc + 1] = v.y;
    tile[lr + 32 * j][lc + 2] = v.z;
    tile[lr + 32 * j][lc + 3] = v.w;
  }
  __syncthreads();
  const int sn = t >> 3;
  const int sh = (t & 7) * 8;
  half8 v;
  #pragma unroll
  for (int c = 0; c < 8; ++c) v[c] = (_Float16)tile[sh + c][sn];
  *(half8*)(dst + (size_t)(n0 + sn) * HIDDEN + h0 + sh) = v;
}

// ---- out[b][q] = b2[q] (atomics accumulate on top) ----
__global__ __launch_bounds__(256) void init_out_kernel(float* __restrict__ out,
                                                       const float* __restrict__ b2) {
  const int i = blockIdx.x * 256 + threadIdx.x;
  out[i] = b2[i & (QUANT - 1)];
}

// ---- fused GEMM + bias + GELU + W2-reduction ----
// 256x256 tile, ring-4 double... quadruple-buffered BK=32 K-tiles, counted vmcnt.
// Pipeline invariant (per thread, 4 gload_lds per tile):
//   phase t: stage tile t+3 into slot (t+3)&3 == (t-1)&3 (consumed in phase t-1);
//   end of phase t: s_waitcnt vmcnt(8) -> tile t+1 landed while tiles t+2,t+3
//   (8 ops) stay in flight across the raw s_barrier. Never drains to 0.
// LDS swizzle: logical kgroup kg stored at physical slot kg ^ ((row>>1)&3);
// with 64 B rows the bank-quad = (4*(row&1) + slot) & 7, so 8 consecutive
// lanes of a frag ds_read_b128 hit all 8 bank-quads exactly once.
__global__ __launch_bounds__(512, 2) void qhead_gemm_kernel(
    const _Float16* __restrict__ A,   // [BATCH][HIDDEN] fp16
    const _Float16* __restrict__ BT,  // [QUANT][HALFD][HIDDEN] fp16
    const float* __restrict__ b1,     // [QUANT][HALFD]
    const float* __restrict__ W2,     // [QUANT][HALFD]
    float* __restrict__ out) {        // [BATCH][QUANT]
  extern __shared__ _Float16 lds[];   // 4 * (A 16KB + B 16KB) = 128 KB

  const int tid  = threadIdx.x;
  const int lane = tid & 63;
  const int wave = tid >> 6;
  const int wm = wave >> 2, wn = wave & 3;   // 2 x 4 waves
  const int r31 = lane & 31, l5 = lane >> 5;
  const int fsw = (r31 >> 1) & 3;            // read-side swizzle term

  // XCD-bijective block swizzle (2048 % 8 == 0)
  const int flat = blockIdx.x;
  const int wg = (flat & 7) * 256 + (flat >> 3);
  const int mb = wg >> 6;          // 0..31
  const int qn = wg & 63;
  const int q  = qn >> 2;          // head
  const int nb = qn & 3;           // 256-col block within head
  const int m0 = mb << 8;

  const _Float16* Ablk = A + (size_t)m0 * HIDDEN;
  const _Float16* Bblk = BT + ((size_t)q * HALFD + nb * BN) * HIDDEN;

  // Staging: chunk c = tid (+512) -> (row = c>>2, phys slot = c&3).
  // LDS dest linear (gload_lds requirement); inverse swizzle on GLOBAL source:
  // logical kgroup = (c&3) ^ ((row>>1)&3).  (row+128 keeps the same kgroup.)
  const int srow = tid >> 2;                      // 0..127
  const int skg  = (tid & 3) ^ ((srow >> 1) & 3);
  const _Float16* agp = Ablk + (size_t)srow * HIDDEN + skg * 8;
  const _Float16* bgp = Bblk + (size_t)srow * HIDDEN + skg * 8;

  // frag row bases (half-index, row stride BKT=32 halfs)
  int aoff[4], boff[2];
  #pragma unroll
  for (int mf = 0; mf < 4; ++mf) aoff[mf] = (wm * 128 + mf * 32 + r31) * BKT;
  #pragma unroll
  for (int nf = 0; nf < 2; ++nf) boff[nf] = (wn * 64 + nf * 32 + r31) * BKT + A_HALFS;

  floatx16 acc[4][2];
  #pragma unroll
  for (int mf = 0; mf < 4; ++mf)
    #pragma unroll
    for (int nf = 0; nf < 2; ++nf)
      #pragma unroll
      for (int i = 0; i < 16; ++i) acc[mf][nf][i] = 0.f;

#define STAGE(ts_) do {                                                    \
    const int ts = (ts_);                                                  \
    const int kc = ((ts < NT) ? ts : (ts - NT)) * BKT; /* wrapped tail */  \
    _Float16* ld = lds + (ts & 3) * SLOT_HALFS + tid * 8;                  \
    load_lds16(agp + kc, ld);                                              \
    load_lds16(agp + kc + (size_t)128 * HIDDEN, ld + 4096);                \
    load_lds16(bgp + kc, ld + A_HALFS);                                    \
    load_lds16(bgp + kc + (size_t)128 * HIDDEN, ld + A_HALFS + 4096);      \
  } while (0)

  // prologue: 3 tiles in flight (12 ops); tile 0 landed once <=8 outstanding
  STAGE(0); STAGE(1); STAGE(2);
  asm volatile("s_waitcnt vmcnt(8)\n\ts_barrier" ::: "memory");

  #pragma unroll 4
  for (int t = 0; t < NT; ++t) {
    STAGE(t + 3);
    const _Float16* ls = lds + (t & 3) * SLOT_HALFS;
    __builtin_amdgcn_s_setprio(1);
    #pragma unroll
    for (int ks = 0; ks < 2; ++ks) {
      // lane wants kgroup w = 2*ks + l5 at physical slot w ^ fsw
      const int p = (((ks << 1) | l5) ^ fsw) << 3;
      half8 af[4], bf[2];
      #pragma unroll
      for (int mf = 0; mf < 4; ++mf) af[mf] = *(const half8*)(ls + aoff[mf] + p);
      #pragma unroll
      for (int nf = 0; nf < 2; ++nf) bf[nf] = *(const half8*)(ls + boff[nf] + p);
      #pragma unroll
      for (int mf = 0; mf < 4; ++mf)
        #pragma unroll
        for (int nf = 0; nf < 2; ++nf)
          acc[mf][nf] = __builtin_amdgcn_mfma_f32_32x32x16_f16(af[mf], bf[nf], acc[mf][nf], 0, 0, 0);
    }
    __builtin_amdgcn_s_setprio(0);
    // tile t+1 ready; tiles t+2,t+3 (8 ops/thread) remain in flight
    asm volatile("s_waitcnt vmcnt(8) lgkmcnt(0)\n\ts_barrier" ::: "memory");
  }
#undef STAGE

  // ---- epilogue: bias + exact GELU + *W2, reduce over this wave's 64 columns ----
  // 32x32 C/D layout: col = lane&31, row = (reg&3) + 8*(reg>>2) + 4*(lane>>5)
  const int colb = nb * BN + wn * 64;
  #pragma unroll
  for (int mf = 0; mf < 4; ++mf) {
    float rs[16];
    #pragma unroll
    for (int r = 0; r < 16; ++r) rs[r] = 0.f;
    #pragma unroll
    for (int nf = 0; nf < 2; ++nf) {
      const int ncol = colb + nf * 32 + r31;
      const float b1v = b1[q * HALFD + ncol];
      const float w2v = W2[q * HALFD + ncol];
      #pragma unroll
      for (int r = 0; r < 16; ++r)
        rs[r] += gelu_exact(acc[mf][nf][r] + b1v) * w2v;
    }
    // butterfly-sum across the 32 column-lanes (low 5 lane bits)
    #pragma unroll
    for (int r = 0; r < 16; ++r) {
      float v = rs[r];
      v += __shfl_xor(v, 1, 64);
      v += __shfl_xor(v, 2, 64);
      v += __shfl_xor(v, 4, 64);
      v += __shfl_xor(v, 8, 64);
      v += __shfl_xor(v, 16, 64);
      rs[r] = v;
    }
    if (r31 == 0) {
      const int mbase = m0 + wm * 128 + mf * 32 + 4 * l5;
      #pragma unroll
      for (int r = 0; r < 16; ++r) {
        const int mrow = mbase + (r & 3) + 8 * (r >> 2);
        atomicAdd(&out[(size_t)mrow * QUANT + q], rs[r]);
      }
    }
  }
}

extern "C" void kernel_launch(void* const* d_in, const int* in_sizes, int n_in,
                              void* d_out, int out_size, void* d_ws, size_t ws_size,
                              hipStream_t stream) {
  const float* x  = (const float*)d_in[0];
  const float* W1 = (const float*)d_in[1];
  const float* b1 = (const float*)d_in[2];
  const float* W2 = (const float*)d_in[3];
  const float* b2 = (const float*)d_in[4];
  float* out = (float*)d_out;

  _Float16* xh  = (_Float16*)d_ws;                                   // 32 MB
  _Float16* w1t = (_Float16*)((char*)d_ws +
                  (size_t)BATCH * HIDDEN * sizeof(_Float16));        // 64 MB

  static int lds_cfg = 0;
  if (!lds_cfg) {
    hipFuncSetAttribute(reinterpret_cast<const void*>(qhead_gemm_kernel),
                        hipFuncAttributeMaxDynamicSharedMemorySize, 131072);
    lds_cfg = 1;
  }

  convert_x_kernel<<<BATCH * HIDDEN / (256 * 8), 256, 0, stream>>>(x, xh);
  transpose_w1_kernel<<<dim3(HALFD / 32, HIDDEN / 64, QUANT), 256, 0, stream>>>(W1, w1t);
  init_out_kernel<<<BATCH * QUANT / 256, 256, 0, stream>>>(out, b2);
  qhead_gemm_kernel<<<dim3(BATCH / BM * (QUANT * HALFD / BN)), 512, 131072, stream>>>(
      xh, w1t, b1, W2, out);
}

// Round 2
// 881.020 us; speedup vs baseline: 1.0592x; 1.0422x over previous
//
#include <hip/hip_runtime.h>

#define HIDDEN 2048
#define QUANT  16
#define BATCH  8192
#define HALFD  1024

// GEMM geometry: 256x256 tile, ring-4 of BK=32 K-tiles, 8 waves (2m x 4n)
#define BM 256
#define BN 256
#define BKT 32
#define NT (HIDDEN / BKT)            // 64 K-tiles
#define NT2 (NT / 2)                 // 32 iterations (2 tiles each)
#define A_HALFS (BM * BKT)           // 8192 halfs = 16 KB per A slot
#define SLOT_HALFS (2 * A_HALFS)     // A+B per slot = 32 KB; x4 slots = 128 KB

typedef _Float16 half8  __attribute__((ext_vector_type(8)));
typedef float    floatx16 __attribute__((ext_vector_type(16)));

__device__ __forceinline__ void load_lds16(const void* gptr, void* lptr) {
  __builtin_amdgcn_global_load_lds(
      (const __attribute__((address_space(1))) void*)gptr,
      (__attribute__((address_space(3))) void*)lptr, 16, 0, 0);
}

// exact-GELU via Abramowitz-Stegun 7.1.26 erf (|eps_erf| <= 1.5e-7)
__device__ __forceinline__ float gelu_exact(float v) {
  const float z  = 0.7071067811865476f * v;
  const float az = fabsf(z);
  const float t  = __builtin_amdgcn_rcpf(1.0f + 0.3275911f * az);
  const float p  = t * (0.254829592f +
                   t * (-0.284496736f +
                   t * (1.421413741f +
                   t * (-1.453152027f +
                   t * 1.061405429f))));
  float er = 1.0f - p * __expf(-az * az);
  er = copysignf(er, z);
  return 0.5f * v * (1.0f + er);
}

// ---- x fp32 -> fp16 ----
__global__ __launch_bounds__(256) void convert_x_kernel(const float* __restrict__ x,
                                                        _Float16* __restrict__ xh) {
  const int i = (blockIdx.x * 256 + threadIdx.x) * 8;
  const float4 a = *(const float4*)(x + i);
  const float4 b = *(const float4*)(x + i + 4);
  half8 h;
  h[0] = (_Float16)a.x; h[1] = (_Float16)a.y; h[2] = (_Float16)a.z; h[3] = (_Float16)a.w;
  h[4] = (_Float16)b.x; h[5] = (_Float16)b.y; h[6] = (_Float16)b.z; h[7] = (_Float16)b.w;
  *(half8*)(xh + i) = h;
}

// ---- W1 [Q][H][N] fp32 -> W1T [Q][N][H] fp16 ----
__global__ __launch_bounds__(256) void transpose_w1_kernel(const float* __restrict__ W1,
                                                           _Float16* __restrict__ W1T) {
  __shared__ float tile[64][33];
  const int q  = blockIdx.z;
  const int h0 = blockIdx.y * 64;
  const int n0 = blockIdx.x * 32;
  const float* src = W1 + (size_t)q * HIDDEN * HALFD;
  _Float16*    dst = W1T + (size_t)q * HALFD * HIDDEN;
  const int t  = threadIdx.x;
  const int lr = t >> 3;
  const int lc = (t & 7) * 4;
  #pragma unroll
  for (int j = 0; j < 2; ++j) {
    const float4 v = *(const float4*)(src + (size_t)(h0 + lr + 32 * j) * HALFD + n0 + lc);
    tile[lr + 32 * j][lc + 0] = v.x;
    tile[lr + 32 * j][lc + 1] = v.y;
    tile[lr + 32 * j][lc + 2] = v.z;
    tile[lr + 32 * j][lc + 3] = v.w;
  }
  __syncthreads();
  const int sn = t >> 3;
  const int sh = (t & 7) * 8;
  half8 v;
  #pragma unroll
  for (int c = 0; c < 8; ++c) v[c] = (_Float16)tile[sh + c][sn];
  *(half8*)(dst + (size_t)(n0 + sn) * HIDDEN + h0 + sh) = v;
}

// ---- out[b][q] = b2[q] (atomics accumulate on top) ----
__global__ __launch_bounds__(256) void init_out_kernel(float* __restrict__ out,
                                                       const float* __restrict__ b2) {
  const int i = blockIdx.x * 256 + threadIdx.x;
  out[i] = b2[i & (QUANT - 1)];
}

// ---- fused GEMM + bias + GELU + W2-reduction ----
// m201-style phase schedule on a ring-4 of BK=32 tiles.
// Iteration t covers K-tiles 2t (slot (2t)&3) and 2t+1 in 4 phases; each
// phase = {6 ds_read_b128 (one k-slice) | 2-load stage chunk | s_barrier |
// lgkmcnt(0) | 8 MFMA under setprio(1) | [vmcnt(8) on even phases] | s_barrier}.
// Stage cadence: P1=A(2t+3), P2=B(2t+3), P3=A(2t+4), P4=B(2t+4).
//  - slot-safety: chunk's dest slot was last READ >=1 phase earlier; phase-end
//    barriers retire reads cross-wave (every wave passed lgkmcnt(0) first).
//  - vmcnt(8) at P2/P4 end = "all but last 4 chunks landed" -> tile needed
//    2 phases later is resident; 8 loads stay in flight across every barrier.
// LDS swizzle (verified R1): logical kgroup kg stored at slot kg ^ ((row>>1)&3);
// staging applies the inverse on the GLOBAL source, LDS dest stays linear.
__global__ __launch_bounds__(512, 2) void qhead_gemm_kernel(
    const _Float16* __restrict__ A,   // [BATCH][HIDDEN] fp16
    const _Float16* __restrict__ BT,  // [QUANT][HALFD][HIDDEN] fp16
    const float* __restrict__ b1,     // [QUANT][HALFD]
    const float* __restrict__ W2,     // [QUANT][HALFD]
    float* __restrict__ out) {        // [BATCH][QUANT]
  extern __shared__ _Float16 lds[];   // 4 * (A 16KB + B 16KB) = 128 KB

  const int tid  = threadIdx.x;
  const int lane = tid & 63;
  const int wave = tid >> 6;
  const int wm = wave >> 2, wn = wave & 3;   // 2 x 4 waves
  const int r31 = lane & 31, l5 = lane >> 5;
  const int fsw = (r31 >> 1) & 3;            // read-side swizzle term

  // XCD-bijective block swizzle (2048 % 8 == 0)
  const int flat = blockIdx.x;
  const int wg = (flat & 7) * 256 + (flat >> 3);
  const int mb = wg >> 6;          // 0..31
  const int qn = wg & 63;
  const int q  = qn >> 2;          // head
  const int nb = qn & 3;           // 256-col block within head
  const int m0 = mb << 8;

  const _Float16* Ablk = A + (size_t)m0 * HIDDEN;
  const _Float16* Bblk = BT + ((size_t)q * HALFD + nb * BN) * HIDDEN;

  // Staging: chunk c = tid -> (row = c>>2, phys slot = c&3); LDS dest linear,
  // inverse swizzle on GLOBAL source: logical kgroup = (c&3) ^ ((row>>1)&3).
  const int srow = tid >> 2;                      // 0..127
  const int skg  = (tid & 3) ^ ((srow >> 1) & 3);
  const _Float16* agp = Ablk + (size_t)srow * HIDDEN + skg * 8;
  const _Float16* bgp = Bblk + (size_t)srow * HIDDEN + skg * 8;

  // frag row bases (half-index, row stride BKT=32 halfs)
  int aoff[4], boff[2];
  #pragma unroll
  for (int mf = 0; mf < 4; ++mf) aoff[mf] = (wm * 128 + mf * 32 + r31) * BKT;
  #pragma unroll
  for (int nf = 0; nf < 2; ++nf) boff[nf] = (wn * 64 + nf * 32 + r31) * BKT + A_HALFS;

  floatx16 acc[4][2];
  #pragma unroll
  for (int mf = 0; mf < 4; ++mf)
    #pragma unroll
    for (int nf = 0; nf < 2; ++nf)
      #pragma unroll
      for (int i = 0; i < 16; ++i) acc[mf][nf][i] = 0.f;

#define STAGE_A(ts_) do {                                                  \
    const int ts_a = (ts_);                                                \
    const int kc_a = ((ts_a < NT) ? ts_a : (ts_a - NT)) * BKT;             \
    _Float16* ld_a = lds + (ts_a & 3) * SLOT_HALFS + tid * 8;              \
    load_lds16(agp + kc_a, ld_a);                                          \
    load_lds16(agp + kc_a + (size_t)128 * HIDDEN, ld_a + 4096);            \
  } while (0)

#define STAGE_B(ts_) do {                                                  \
    const int ts_b = (ts_);                                                \
    const int kc_b = ((ts_b < NT) ? ts_b : (ts_b - NT)) * BKT;             \
    _Float16* ld_b = lds + (ts_b & 3) * SLOT_HALFS + A_HALFS + tid * 8;    \
    load_lds16(bgp + kc_b, ld_b);                                          \
    load_lds16(bgp + kc_b + (size_t)128 * HIDDEN, ld_b + 4096);            \
  } while (0)

#define PHASE(LS, KS, STAGE_STMT, DO_VM) do {                              \
    const _Float16* ls_ = (LS);                                            \
    const int p_ = (((KS << 1) | l5) ^ fsw) << 3;                          \
    half8 af0 = *(const half8*)(ls_ + aoff[0] + p_);                       \
    half8 af1 = *(const half8*)(ls_ + aoff[1] + p_);                       \
    half8 af2 = *(const half8*)(ls_ + aoff[2] + p_);                       \
    half8 af3 = *(const half8*)(ls_ + aoff[3] + p_);                       \
    half8 bf0 = *(const half8*)(ls_ + boff[0] + p_);                       \
    half8 bf1 = *(const half8*)(ls_ + boff[1] + p_);                       \
    STAGE_STMT;                                                            \
    asm volatile("s_barrier" ::: "memory");                                \
    asm volatile("s_waitcnt lgkmcnt(0)" ::: "memory");                     \
    __builtin_amdgcn_sched_barrier(0);                                     \
    __builtin_amdgcn_s_setprio(1);                                         \
    acc[0][0] = __builtin_amdgcn_mfma_f32_32x32x16_f16(af0, bf0, acc[0][0], 0, 0, 0); \
    acc[0][1] = __builtin_amdgcn_mfma_f32_32x32x16_f16(af0, bf1, acc[0][1], 0, 0, 0); \
    acc[1][0] = __builtin_amdgcn_mfma_f32_32x32x16_f16(af1, bf0, acc[1][0], 0, 0, 0); \
    acc[1][1] = __builtin_amdgcn_mfma_f32_32x32x16_f16(af1, bf1, acc[1][1], 0, 0, 0); \
    acc[2][0] = __builtin_amdgcn_mfma_f32_32x32x16_f16(af2, bf0, acc[2][0], 0, 0, 0); \
    acc[2][1] = __builtin_amdgcn_mfma_f32_32x32x16_f16(af2, bf1, acc[2][1], 0, 0, 0); \
    acc[3][0] = __builtin_amdgcn_mfma_f32_32x32x16_f16(af3, bf0, acc[3][0], 0, 0, 0); \
    acc[3][1] = __builtin_amdgcn_mfma_f32_32x32x16_f16(af3, bf1, acc[3][1], 0, 0, 0); \
    __builtin_amdgcn_s_setprio(0);                                         \
    __builtin_amdgcn_sched_barrier(0);                                     \
    if (DO_VM) asm volatile("s_waitcnt vmcnt(8)" ::: "memory");            \
    asm volatile("s_barrier" ::: "memory");                                \
  } while (0)

  // prologue: chunks A0,B0,A1,B1,A2,B2 (12 loads); tile0 landed once <=8 out
  STAGE_A(0); STAGE_B(0); STAGE_A(1); STAGE_B(1); STAGE_A(2); STAGE_B(2);
  asm volatile("s_waitcnt vmcnt(8)\n\ts_barrier" ::: "memory");

  #pragma unroll 2
  for (int t = 0; t < NT2; ++t) {
    const _Float16* ls0 = lds + ((2 * t) & 3) * SLOT_HALFS;
    const _Float16* ls1 = lds + ((2 * t + 1) & 3) * SLOT_HALFS;
    PHASE(ls0, 0, STAGE_A(2 * t + 3), 0);
    PHASE(ls0, 1, STAGE_B(2 * t + 3), 1);
    PHASE(ls1, 0, STAGE_A(2 * t + 4), 0);
    PHASE(ls1, 1, STAGE_B(2 * t + 4), 1);
  }
#undef PHASE
#undef STAGE_A
#undef STAGE_B

  // ---- epilogue: bias + exact GELU + *W2, reduce over this wave's 64 columns ----
  // 32x32 C/D layout: col = lane&31, row = (reg&3) + 8*(reg>>2) + 4*(lane>>5)
  const int colb = nb * BN + wn * 64;
  #pragma unroll
  for (int mf = 0; mf < 4; ++mf) {
    float rs[16];
    #pragma unroll
    for (int r = 0; r < 16; ++r) rs[r] = 0.f;
    #pragma unroll
    for (int nf = 0; nf < 2; ++nf) {
      const int ncol = colb + nf * 32 + r31;
      const float b1v = b1[q * HALFD + ncol];
      const float w2v = W2[q * HALFD + ncol];
      #pragma unroll
      for (int r = 0; r < 16; ++r)
        rs[r] += gelu_exact(acc[mf][nf][r] + b1v) * w2v;
    }
    // butterfly-sum across the 32 column-lanes (low 5 lane bits)
    #pragma unroll
    for (int r = 0; r < 16; ++r) {
      float v = rs[r];
      v += __shfl_xor(v, 1, 64);
      v += __shfl_xor(v, 2, 64);
      v += __shfl_xor(v, 4, 64);
      v += __shfl_xor(v, 8, 64);
      v += __shfl_xor(v, 16, 64);
      rs[r] = v;
    }
    if (r31 == 0) {
      const int mbase = m0 + wm * 128 + mf * 32 + 4 * l5;
      #pragma unroll
      for (int r = 0; r < 16; ++r) {
        const int mrow = mbase + (r & 3) + 8 * (r >> 2);
        atomicAdd(&out[(size_t)mrow * QUANT + q], rs[r]);
      }
    }
  }
}

extern "C" void kernel_launch(void* const* d_in, const int* in_sizes, int n_in,
                              void* d_out, int out_size, void* d_ws, size_t ws_size,
                              hipStream_t stream) {
  const float* x  = (const float*)d_in[0];
  const float* W1 = (const float*)d_in[1];
  const float* b1 = (const float*)d_in[2];
  const float* W2 = (const float*)d_in[3];
  const float* b2 = (const float*)d_in[4];
  float* out = (float*)d_out;

  _Float16* xh  = (_Float16*)d_ws;                                   // 32 MB
  _Float16* w1t = (_Float16*)((char*)d_ws +
                  (size_t)BATCH * HIDDEN * sizeof(_Float16));        // 64 MB

  static int lds_cfg = 0;
  if (!lds_cfg) {
    hipFuncSetAttribute(reinterpret_cast<const void*>(qhead_gemm_kernel),
                        hipFuncAttributeMaxDynamicSharedMemorySize, 131072);
    lds_cfg = 1;
  }

  convert_x_kernel<<<BATCH * HIDDEN / (256 * 8), 256, 0, stream>>>(x, xh);
  transpose_w1_kernel<<<dim3(HALFD / 32, HIDDEN / 64, QUANT), 256, 0, stream>>>(W1, w1t);
  init_out_kernel<<<BATCH * QUANT / 256, 256, 0, stream>>>(out, b2);
  qhead_gemm_kernel<<<dim3(BATCH / BM * (QUANT * HALFD / BN)), 512, 131072, stream>>>(
      xh, w1t, b1, W2, out);
}

// Round 3
// 877.211 us; speedup vs baseline: 1.0638x; 1.0043x over previous
//
#include <hip/hip_runtime.h>

#define HIDDEN 2048
#define QUANT  16
#define BATCH  8192
#define HALFD  1024

// GEMM geometry: 256x256 tile, ring-4 of BK=32 K-tiles, 8 waves (2m x 4n)
#define BM 256
#define BN 256
#define BKT 32
#define NT (HIDDEN / BKT)            // 64 K-tiles
#define NT2 (NT / 2)                 // 32 iterations (2 tiles each)
#define A_HALFS (BM * BKT)           // 8192 halfs = 16 KB per A slot
#define SLOT_HALFS (2 * A_HALFS)     // A+B per slot = 32 KB; x4 slots = 128 KB

typedef _Float16 half8  __attribute__((ext_vector_type(8)));
typedef float    floatx16 __attribute__((ext_vector_type(16)));

__device__ __forceinline__ void load_lds16(const void* gptr, void* lptr) {
  __builtin_amdgcn_global_load_lds(
      (const __attribute__((address_space(1))) void*)gptr,
      (__attribute__((address_space(3))) void*)lptr, 16, 0, 0);
}

// exact-GELU via Abramowitz-Stegun 7.1.26 erf (|eps_erf| <= 1.5e-7)
__device__ __forceinline__ float gelu_exact(float v) {
  const float z  = 0.7071067811865476f * v;
  const float az = fabsf(z);
  const float t  = __builtin_amdgcn_rcpf(1.0f + 0.3275911f * az);
  const float p  = t * (0.254829592f +
                   t * (-0.284496736f +
                   t * (1.421413741f +
                   t * (-1.453152027f +
                   t * 1.061405429f))));
  float er = 1.0f - p * __expf(-az * az);
  er = copysignf(er, z);
  return 0.5f * v * (1.0f + er);
}

// ---- x fp32 -> fp16 ----
__global__ __launch_bounds__(256) void convert_x_kernel(const float* __restrict__ x,
                                                        _Float16* __restrict__ xh) {
  const int i = (blockIdx.x * 256 + threadIdx.x) * 8;
  const float4 a = *(const float4*)(x + i);
  const float4 b = *(const float4*)(x + i + 4);
  half8 h;
  h[0] = (_Float16)a.x; h[1] = (_Float16)a.y; h[2] = (_Float16)a.z; h[3] = (_Float16)a.w;
  h[4] = (_Float16)b.x; h[5] = (_Float16)b.y; h[6] = (_Float16)b.z; h[7] = (_Float16)b.w;
  *(half8*)(xh + i) = h;
}

// ---- W1 [Q][H][N] fp32 -> W1T [Q][N][H] fp16 ----
__global__ __launch_bounds__(256) void transpose_w1_kernel(const float* __restrict__ W1,
                                                           _Float16* __restrict__ W1T) {
  __shared__ float tile[64][33];
  const int q  = blockIdx.z;
  const int h0 = blockIdx.y * 64;
  const int n0 = blockIdx.x * 32;
  const float* src = W1 + (size_t)q * HIDDEN * HALFD;
  _Float16*    dst = W1T + (size_t)q * HALFD * HIDDEN;
  const int t  = threadIdx.x;
  const int lr = t >> 3;
  const int lc = (t & 7) * 4;
  #pragma unroll
  for (int j = 0; j < 2; ++j) {
    const float4 v = *(const float4*)(src + (size_t)(h0 + lr + 32 * j) * HALFD + n0 + lc);
    tile[lr + 32 * j][lc + 0] = v.x;
    tile[lr + 32 * j][lc + 1] = v.y;
    tile[lr + 32 * j][lc + 2] = v.z;
    tile[lr + 32 * j][lc + 3] = v.w;
  }
  __syncthreads();
  const int sn = t >> 3;
  const int sh = (t & 7) * 8;
  half8 v;
  #pragma unroll
  for (int c = 0; c < 8; ++c) v[c] = (_Float16)tile[sh + c][sn];
  *(half8*)(dst + (size_t)(n0 + sn) * HIDDEN + h0 + sh) = v;
}

// ---- out[b][q] = b2[q] (atomics accumulate on top) ----
__global__ __launch_bounds__(256) void init_out_kernel(float* __restrict__ out,
                                                       const float* __restrict__ b2) {
  const int i = blockIdx.x * 256 + threadIdx.x;
  out[i] = b2[i & (QUANT - 1)];
}

// ---- fused GEMM + bias + GELU + W2-reduction ----
// Phase-pipelined ring-4 (BK=32): fragments REGISTER-DOUBLE-BUFFERED one phase
// deep. Phase = {issue 6 ds_reads for NEXT phase | 2-load stage | lgkmcnt(6)
// (prev reads done, new 6 stay in flight across the barrier) | 8 MFMA under
// setprio | [vmcnt(4) on P1/P3] | s_barrier}.
// Residency: vmcnt(4) at end-P1 retires through A(2t+2) => tile 2t+1 resident
// before P2's read-ahead; vmcnt(4) at end-P3 retires through A(2t+3) => tile
// 2t+2 resident before P4's read-ahead. P2/P4 need no vmcnt (pipeline deepens,
// never drains; bounded at ~16 loads by the P1/P3 waits).
// Slot-overwrite safety with ONE barrier/phase: all reads of a slot complete
// before their wave's phase-end barrier (lgkmcnt), and the overwriting stage
// issues only after that barrier.
// LDS swizzle: logical kgroup kg stored at slot kg ^ ((row>>1)&3); staging
// applies the inverse on the GLOBAL source, LDS dest stays linear.
__global__ __launch_bounds__(512, 2) void qhead_gemm_kernel(
    const _Float16* __restrict__ A,   // [BATCH][HIDDEN] fp16
    const _Float16* __restrict__ BT,  // [QUANT][HALFD][HIDDEN] fp16
    const float* __restrict__ b1,     // [QUANT][HALFD]
    const float* __restrict__ W2,     // [QUANT][HALFD]
    float* __restrict__ out) {        // [BATCH][QUANT]
  extern __shared__ _Float16 lds[];   // 4 * (A 16KB + B 16KB) = 128 KB

  const int tid  = threadIdx.x;
  const int lane = tid & 63;
  const int wave = tid >> 6;
  const int wm = wave >> 2, wn = wave & 3;   // 2 x 4 waves
  const int r31 = lane & 31, l5 = lane >> 5;
  const int fsw = (r31 >> 1) & 3;            // read-side swizzle term

  // XCD-bijective block swizzle (2048 % 8 == 0)
  const int flat = blockIdx.x;
  const int wg = (flat & 7) * 256 + (flat >> 3);
  const int mb = wg >> 6;          // 0..31
  const int qn = wg & 63;
  const int q  = qn >> 2;          // head
  const int nb = qn & 3;           // 256-col block within head
  const int m0 = mb << 8;

  const _Float16* Ablk = A + (size_t)m0 * HIDDEN;
  const _Float16* Bblk = BT + ((size_t)q * HALFD + nb * BN) * HIDDEN;

  // Staging: chunk c = tid -> (row = c>>2, phys slot = c&3); LDS dest linear,
  // inverse swizzle on GLOBAL source: logical kgroup = (c&3) ^ ((row>>1)&3).
  const int srow = tid >> 2;                      // 0..127
  const int skg  = (tid & 3) ^ ((srow >> 1) & 3);
  const _Float16* agp = Ablk + (size_t)srow * HIDDEN + skg * 8;
  const _Float16* bgp = Bblk + (size_t)srow * HIDDEN + skg * 8;

  // frag row bases (half-index, row stride BKT=32 halfs)
  int aoff[4], boff[2];
  #pragma unroll
  for (int mf = 0; mf < 4; ++mf) aoff[mf] = (wm * 128 + mf * 32 + r31) * BKT;
  #pragma unroll
  for (int nf = 0; nf < 2; ++nf) boff[nf] = (wn * 64 + nf * 32 + r31) * BKT + A_HALFS;

  floatx16 acc[4][2];
  #pragma unroll
  for (int mf = 0; mf < 4; ++mf)
    #pragma unroll
    for (int nf = 0; nf < 2; ++nf)
      #pragma unroll
      for (int i = 0; i < 16; ++i) acc[mf][nf][i] = 0.f;

  half8 r0[6], r1[6];

#define STAGE_A(ts_) do {                                                  \
    const int ts_a = (ts_);                                                \
    const int kc_a = ((ts_a < NT) ? ts_a : (ts_a - NT)) * BKT;             \
    _Float16* ld_a = lds + (ts_a & 3) * SLOT_HALFS + tid * 8;              \
    load_lds16(agp + kc_a, ld_a);                                          \
    load_lds16(agp + kc_a + (size_t)128 * HIDDEN, ld_a + 4096);            \
  } while (0)

#define STAGE_B(ts_) do {                                                  \
    const int ts_b = (ts_);                                                \
    const int kc_b = ((ts_b < NT) ? ts_b : (ts_b - NT)) * BKT;             \
    _Float16* ld_b = lds + (ts_b & 3) * SLOT_HALFS + A_HALFS + tid * 8;    \
    load_lds16(bgp + kc_b, ld_b);                                          \
    load_lds16(bgp + kc_b + (size_t)128 * HIDDEN, ld_b + 4096);            \
  } while (0)

// CUR: frags to compute now; NXT: issue reads for next phase from LSN/KSN.
#define PHASE(CUR, NXT, LSN, KSN, STAGE_STMT, DO_VM4) do {                 \
    const _Float16* lsn_ = (LSN);                                          \
    const int pn_ = ((((KSN) << 1) | l5) ^ fsw) << 3;                      \
    NXT[0] = *(const half8*)(lsn_ + aoff[0] + pn_);                        \
    NXT[1] = *(const half8*)(lsn_ + aoff[1] + pn_);                        \
    NXT[2] = *(const half8*)(lsn_ + aoff[2] + pn_);                        \
    NXT[3] = *(const half8*)(lsn_ + aoff[3] + pn_);                        \
    NXT[4] = *(const half8*)(lsn_ + boff[0] + pn_);                        \
    NXT[5] = *(const half8*)(lsn_ + boff[1] + pn_);                        \
    STAGE_STMT;                                                            \
    asm volatile("s_waitcnt lgkmcnt(6)" ::: "memory");                     \
    __builtin_amdgcn_sched_barrier(0);                                     \
    __builtin_amdgcn_s_setprio(1);                                         \
    acc[0][0] = __builtin_amdgcn_mfma_f32_32x32x16_f16(CUR[0], CUR[4], acc[0][0], 0, 0, 0); \
    acc[0][1] = __builtin_amdgcn_mfma_f32_32x32x16_f16(CUR[0], CUR[5], acc[0][1], 0, 0, 0); \
    acc[1][0] = __builtin_amdgcn_mfma_f32_32x32x16_f16(CUR[1], CUR[4], acc[1][0], 0, 0, 0); \
    acc[1][1] = __builtin_amdgcn_mfma_f32_32x32x16_f16(CUR[1], CUR[5], acc[1][1], 0, 0, 0); \
    acc[2][0] = __builtin_amdgcn_mfma_f32_32x32x16_f16(CUR[2], CUR[4], acc[2][0], 0, 0, 0); \
    acc[2][1] = __builtin_amdgcn_mfma_f32_32x32x16_f16(CUR[2], CUR[5], acc[2][1], 0, 0, 0); \
    acc[3][0] = __builtin_amdgcn_mfma_f32_32x32x16_f16(CUR[3], CUR[4], acc[3][0], 0, 0, 0); \
    acc[3][1] = __builtin_amdgcn_mfma_f32_32x32x16_f16(CUR[3], CUR[5], acc[3][1], 0, 0, 0); \
    __builtin_amdgcn_s_setprio(0);                                         \
    __builtin_amdgcn_sched_barrier(0);                                     \
    if (DO_VM4) asm volatile("s_waitcnt vmcnt(4)" ::: "memory");           \
    asm volatile("s_barrier" ::: "memory");                                \
  } while (0)

  // prologue: stage tiles 0..2 (12 loads); vmcnt(8) -> tile0 resident
  STAGE_A(0); STAGE_B(0); STAGE_A(1); STAGE_B(1); STAGE_A(2); STAGE_B(2);
  asm volatile("s_waitcnt vmcnt(8)\n\ts_barrier" ::: "memory");

  // prime r0 with tile0, ks=0
  {
    const int p0 = (l5 ^ fsw) << 3;
    r0[0] = *(const half8*)(lds + aoff[0] + p0);
    r0[1] = *(const half8*)(lds + aoff[1] + p0);
    r0[2] = *(const half8*)(lds + aoff[2] + p0);
    r0[3] = *(const half8*)(lds + aoff[3] + p0);
    r0[4] = *(const half8*)(lds + boff[0] + p0);
    r0[5] = *(const half8*)(lds + boff[1] + p0);
  }

  #pragma unroll 2
  for (int t = 0; t < NT2; ++t) {
    const _Float16* ls0 = lds + ((2 * t) & 3) * SLOT_HALFS;
    const _Float16* ls1 = lds + ((2 * t + 1) & 3) * SLOT_HALFS;
    const _Float16* ls2 = lds + ((2 * t + 2) & 3) * SLOT_HALFS;
    // P1: compute (2t,ks0); read (2t,ks1); vmcnt(4) => tile 2t+1 resident
    PHASE(r0, r1, ls0, 1, STAGE_A(2 * t + 3), 1);
    // P2: compute (2t,ks1); read (2t+1,ks0)
    PHASE(r1, r0, ls1, 0, STAGE_B(2 * t + 3), 0);
    // P3: compute (2t+1,ks0); read (2t+1,ks1); vmcnt(4) => tile 2t+2 resident
    PHASE(r0, r1, ls1, 1, STAGE_A(2 * t + 4), 1);
    // P4: compute (2t+1,ks1); read (2t+2,ks0)  [last iter: wrapped, unused]
    PHASE(r1, r0, ls2, 0, STAGE_B(2 * t + 4), 0);
  }
#undef PHASE
#undef STAGE_A
#undef STAGE_B

  // ---- epilogue: bias + exact GELU + *W2, reduce over this wave's 64 columns ----
  // 32x32 C/D layout: col = lane&31, row = (reg&3) + 8*(reg>>2) + 4*(lane>>5)
  const int colb = nb * BN + wn * 64;
  #pragma unroll
  for (int mf = 0; mf < 4; ++mf) {
    float rs[16];
    #pragma unroll
    for (int r = 0; r < 16; ++r) rs[r] = 0.f;
    #pragma unroll
    for (int nf = 0; nf < 2; ++nf) {
      const int ncol = colb + nf * 32 + r31;
      const float b1v = b1[q * HALFD + ncol];
      const float w2v = W2[q * HALFD + ncol];
      #pragma unroll
      for (int r = 0; r < 16; ++r)
        rs[r] += gelu_exact(acc[mf][nf][r] + b1v) * w2v;
    }
    // butterfly-sum across the 32 column-lanes (low 5 lane bits)
    #pragma unroll
    for (int r = 0; r < 16; ++r) {
      float v = rs[r];
      v += __shfl_xor(v, 1, 64);
      v += __shfl_xor(v, 2, 64);
      v += __shfl_xor(v, 4, 64);
      v += __shfl_xor(v, 8, 64);
      v += __shfl_xor(v, 16, 64);
      rs[r] = v;
    }
    if (r31 == 0) {
      const int mbase = m0 + wm * 128 + mf * 32 + 4 * l5;
      #pragma unroll
      for (int r = 0; r < 16; ++r) {
        const int mrow = mbase + (r & 3) + 8 * (r >> 2);
        atomicAdd(&out[(size_t)mrow * QUANT + q], rs[r]);
      }
    }
  }
}

extern "C" void kernel_launch(void* const* d_in, const int* in_sizes, int n_in,
                              void* d_out, int out_size, void* d_ws, size_t ws_size,
                              hipStream_t stream) {
  const float* x  = (const float*)d_in[0];
  const float* W1 = (const float*)d_in[1];
  const float* b1 = (const float*)d_in[2];
  const float* W2 = (const float*)d_in[3];
  const float* b2 = (const float*)d_in[4];
  float* out = (float*)d_out;

  _Float16* xh  = (_Float16*)d_ws;                                   // 32 MB
  _Float16* w1t = (_Float16*)((char*)d_ws +
                  (size_t)BATCH * HIDDEN * sizeof(_Float16));        // 64 MB

  static int lds_cfg = 0;
  if (!lds_cfg) {
    hipFuncSetAttribute(reinterpret_cast<const void*>(qhead_gemm_kernel),
                        hipFuncAttributeMaxDynamicSharedMemorySize, 131072);
    lds_cfg = 1;
  }

  convert_x_kernel<<<BATCH * HIDDEN / (256 * 8), 256, 0, stream>>>(x, xh);
  transpose_w1_kernel<<<dim3(HALFD / 32, HIDDEN / 64, QUANT), 256, 0, stream>>>(W1, w1t);
  init_out_kernel<<<BATCH * QUANT / 256, 256, 0, stream>>>(out, b2);
  qhead_gemm_kernel<<<dim3(BATCH / BM * (QUANT * HALFD / BN)), 512, 131072, stream>>>(
      xh, w1t, b1, W2, out);
}